// Round 7
// baseline (193.877 us; speedup 1.0000x reference)
//
#include <hip/hip_runtime.h>
#include <hip/hip_bf16.h>
#include <math.h>

// Problem constants
#define T_STEPS 100
#define H_DIM   50
#define Z_DIM   10
#define OUT_DIM 65   // Z + Z*(Z+1)/2 = 10 + 55

// LDS weight row layout (per lane): stride 164 dwords (== 4 mod 32 -> b128
// conflict-free; 656 B row is 16B-aligned). Sections: r @ 0, z @ 52, n @ 104,
// each 52 dwords (50 weights + 2 zero pads).
#define ROW_STRIDE 164
#define SEC_Z      52
#define SEC_N      104

// ---- cross-lane primitives ----
__device__ __forceinline__ float bcast_lane(float v, int lane) {
    return __uint_as_float(__builtin_amdgcn_readlane(__float_as_uint(v), lane));
}
// DPP cross-lane fetch (VALU speed). bound_ctrl=1 -> invalid source reads 0.
template<int CTRL>
__device__ __forceinline__ float dpp_mov(float x) {
    return __uint_as_float((unsigned)__builtin_amdgcn_update_dpp(
        0, (int)__float_as_uint(x), CTRL, 0xF, 0xF, true));
}
#define DPP_SHR1    0x111
#define DPP_SHR2    0x112
#define DPP_SHR4    0x114
#define DPP_SHR8    0x118
#define DPP_BCAST15 0x142
#define DPP_BCAST31 0x143

// ---- fast math ----
__device__ __forceinline__ float fast_rcp(float x) { return __builtin_amdgcn_rcpf(x); }
__device__ __forceinline__ float fast_rsq(float x) { return __builtin_amdgcn_rsqf(x); }
__device__ __forceinline__ float fast_sigmoid(float x) {
    return fast_rcp(1.0f + __expf(-x));
}
__device__ __forceinline__ float fast_tanh(float y) {
    return 1.0f - 2.0f * fast_rcp(__expf(2.0f * y) + 1.0f);
}

// =====================================================================
// Kernel 1: serial recurrence. ONE wave; weights live in LDS (private
// row per lane, conflict-free b128 layout). No barriers anywhere.
// h history -> ws as [T][64] f32.
// =====================================================================
__global__ __launch_bounds__(64, 1)
void gru_recur_kernel(
    const float* __restrict__ carry_init,
    const float* __restrict__ W_hr, const float* __restrict__ b_hr,
    const float* __restrict__ s_r,  const float* __restrict__ o_r,
    const float* __restrict__ W_hz, const float* __restrict__ b_hz,
    const float* __restrict__ s_z,  const float* __restrict__ o_z,
    const float* __restrict__ W_hn, const float* __restrict__ b_hn,
    const float* __restrict__ s_n,  const float* __restrict__ o_n,
    float* __restrict__ ws_h)
{
    __shared__ float wl[64 * ROW_STRIDE];   // 41,984 B

    const int  j     = threadIdx.x;
    const bool valid = (j < H_DIM);
    const int  jc    = valid ? j : 0;

    float* row = &wl[j * ROW_STRIDE];

    // ---- one-time fill: column j of each gate into my private row ----
    // Lane j only ever reads its own row -> no cross-lane sync needed.
    #pragma unroll 1
    for (int i = 0; i < H_DIM; ++i) {
        row[i]           = valid ? W_hr[i * H_DIM + j] : 0.0f;
        row[SEC_Z + i]   = valid ? W_hz[i * H_DIM + j] : 0.0f;
        row[SEC_N + i]   = valid ? W_hn[i * H_DIM + j] : 0.0f;
    }
    row[50]          = 0.0f; row[51]          = 0.0f;   // pads (chunk 12 reads them)
    row[SEC_Z + 50]  = 0.0f; row[SEC_Z + 51]  = 0.0f;
    row[SEC_N + 50]  = 0.0f; row[SEC_N + 51]  = 0.0f;

    const float bjr = valid ? b_hr[jc] : 0.0f;
    const float bjz = valid ? b_hz[jc] : 0.0f;
    const float bjn = valid ? b_hn[jc] : 0.0f;
    const float sr  = s_r[jc], og_r = o_r[jc];
    const float sz  = s_z[jc], og_z = o_z[jc];
    const float sn  = s_n[jc], og_n = o_n[jc];

    float h = valid ? carry_init[jc] : 0.0f;
    const float invH = 1.0f / (float)H_DIM;

    #pragma unroll 1
    for (int t = 0; t < T_STEPS; ++t) {
        // Opaque pointer: the ds_reads below depend on r_, which is
        // "redefined" every iteration -> LICM cannot hoist them into
        // (parked) registers across the t-loop.
        const float* r_ = row;
        asm volatile("" : "+v"(r_));

        // ---- three matvecs from LDS: a_j = b_j + sum_i h_i * W[i][j] ----
        float ar = bjr, az = bjz, an = bjn;
        #pragma unroll
        for (int c = 0; c < 13; ++c) {
            const float4 qr = *(const float4*)(r_ + 4 * c);
            const float4 qz = *(const float4*)(r_ + SEC_Z + 4 * c);
            const float4 qn = *(const float4*)(r_ + SEC_N + 4 * c);
            const float h0 = bcast_lane(h, 4 * c + 0);
            const float h1 = bcast_lane(h, 4 * c + 1);
            const float h2 = bcast_lane(h, 4 * c + 2);
            const float h3 = bcast_lane(h, 4 * c + 3);
            ar = fmaf(h0, qr.x, ar); az = fmaf(h0, qz.x, az); an = fmaf(h0, qn.x, an);
            ar = fmaf(h1, qr.y, ar); az = fmaf(h1, qz.y, az); an = fmaf(h1, qn.y, an);
            ar = fmaf(h2, qr.z, ar); az = fmaf(h2, qz.z, az); an = fmaf(h2, qn.z, an);
            ar = fmaf(h3, qr.w, ar); az = fmaf(h3, qz.w, az); an = fmaf(h3, qn.w, an);
        }

        // ---- LN stats: 6 quantities, interleaved DPP tree (a==0 on invalid lanes) ----
        float mr = ar, qrs = ar * ar;
        float mz = az, qzs = az * az;
        float mn = an, qns = an * an;
        #define STAGE(C)                                        \
            mr += dpp_mov<C>(mr); qrs += dpp_mov<C>(qrs);       \
            mz += dpp_mov<C>(mz); qzs += dpp_mov<C>(qzs);       \
            mn += dpp_mov<C>(mn); qns += dpp_mov<C>(qns);
        STAGE(DPP_SHR1) STAGE(DPP_SHR2) STAGE(DPP_SHR4)
        STAGE(DPP_SHR8) STAGE(DPP_BCAST15) STAGE(DPP_BCAST31)
        #undef STAGE
        mr = bcast_lane(mr, 63); qrs = bcast_lane(qrs, 63);
        mz = bcast_lane(mz, 63); qzs = bcast_lane(qzs, 63);
        mn = bcast_lane(mn, 63); qns = bcast_lane(qns, 63);

        // ---- layernorm + activations ----
        const float mu_r  = mr * invH;
        const float var_r = fmaxf(qrs * invH - mu_r * mu_r, 0.0f);
        const float g_r   = (ar - mu_r) * fast_rsq(var_r + 1e-6f) * sr + og_r;
        const float r     = fast_sigmoid(g_r);

        const float mu_z  = mz * invH;
        const float var_z = fmaxf(qzs * invH - mu_z * mu_z, 0.0f);
        const float g_z   = (az - mu_z) * fast_rsq(var_z + 1e-6f) * sz + og_z;
        const float z     = fast_sigmoid(g_z);

        const float mu_n  = mn * invH;
        const float var_n = fmaxf(qns * invH - mu_n * mu_n, 0.0f);
        const float g_n   = (an - mu_n) * fast_rsq(var_n + 1e-6f) * sn + og_n;
        const float n     = fast_tanh(r * g_n);

        h = n + z * (h - n);                 // (1-z)*n + z*h
        ws_h[t * 64 + j] = h;                // unconditional 64-wide store
    }
}

// =====================================================================
// Kernel 2: dense projection + nat transform. One block per timestep,
// parallel across CUs.
// =====================================================================
__global__ __launch_bounds__(128)
void dense_nat_kernel(
    const float* __restrict__ W_dense, const float* __restrict__ b_dense,
    const float* __restrict__ ws_h, float* __restrict__ out)
{
    const int t   = blockIdx.x;
    const int tid = threadIdx.x;

    __shared__ float hloc[H_DIM];
    __shared__ float dl  [OUT_DIM];
    __shared__ float Lp  [55];
    __shared__ float Li  [55];
    __shared__ float Jsh [100];

    if (tid < H_DIM) hloc[tid] = ws_h[t * 64 + tid];
    __syncthreads();

    if (tid < OUT_DIM) {
        float acc = b_dense[tid];
        #pragma unroll
        for (int i = 0; i < H_DIM; ++i)
            acc = fmaf(hloc[i], W_dense[i * OUT_DIM + tid], acc);
        dl[tid] = acc;
    }
    __syncthreads();

    // Lp = packed lower-tri L with softplus applied to diagonal entries.
    if (tid < 55) {
        float v = dl[Z_DIM + tid];
        const bool isd = (tid==0)|(tid==2)|(tid==5)|(tid==9)|(tid==14)|
                         (tid==20)|(tid==27)|(tid==35)|(tid==44)|(tid==54);
        if (isd) v = (v > 20.0f) ? v : log1pf(__expf(v));
        Lp[tid] = v;
    }
    __syncthreads();

    float* outSigma = out;           // [100][10][10]
    float* outMu    = out + 10000;   // [100][10]
    float* outJ     = out + 11000;   // [100][10][10]
    float* outHnat  = out + 21000;   // [100][10]

    // Map flat tri index -> (a,b), a >= b
    int a = 0;
    {
        #pragma unroll
        for (int x = 1; x < Z_DIM; ++x)
            if (tid >= x * (x + 1) / 2) a = x;
    }
    const int b = tid - a * (a + 1) / 2;

    // Sigma = L @ L^T (one entry per thread)
    if (tid < 55) {
        float s = 0.0f;
        for (int k = 0; k <= b; ++k)
            s = fmaf(Lp[a * (a + 1) / 2 + k], Lp[b * (b + 1) / 2 + k], s);
        outSigma[t * 100 + a * 10 + b] = s;
        outSigma[t * 100 + b * 10 + a] = s;
    }
    if (tid >= 64 && tid < 64 + Z_DIM) outMu[t * 10 + (tid - 64)] = dl[tid - 64];
    __syncthreads();

    // Linv by forward substitution (serial, tiny)
    if (tid == 0) {
        #pragma unroll
        for (int i = 0; i < Z_DIM; ++i) {
            const float d = 1.0f / Lp[i * (i + 1) / 2 + i];
            #pragma unroll
            for (int k = 0; k < i; ++k) {
                float s = 0.0f;
                for (int m = k; m < i; ++m)
                    s = fmaf(Lp[i * (i + 1) / 2 + m], Li[m * (m + 1) / 2 + k], s);
                Li[i * (i + 1) / 2 + k] = -s * d;
            }
            Li[i * (i + 1) / 2 + i] = d;
        }
    }
    __syncthreads();

    // J = Linv^T @ Linv (one entry per thread)
    if (tid < 55) {
        float s = 0.0f;
        for (int m = a; m < Z_DIM; ++m)
            s = fmaf(Li[m * (m + 1) / 2 + a], Li[m * (m + 1) / 2 + b], s);
        outJ[t * 100 + a * 10 + b] = s;
        outJ[t * 100 + b * 10 + a] = s;
        Jsh[a * 10 + b] = s;
        Jsh[b * 10 + a] = s;
    }
    __syncthreads();

    // h_nat = J @ mu
    if (tid < Z_DIM) {
        float s = 0.0f;
        #pragma unroll
        for (int k = 0; k < Z_DIM; ++k)
            s = fmaf(Jsh[tid * 10 + k], dl[k], s);
        outHnat[t * 10 + tid] = s;
    }
}

extern "C" void kernel_launch(void* const* d_in, const int* in_sizes, int n_in,
                              void* d_out, int out_size, void* d_ws, size_t ws_size,
                              hipStream_t stream) {
    const float* p[15];
    for (int i = 0; i < 15; ++i) p[i] = (const float*)d_in[i];
    float* ws_h = (float*)d_ws;   // [T_STEPS][64] f32 = 25600 B

    gru_recur_kernel<<<dim3(1), dim3(64), 0, stream>>>(
        p[0],
        p[1], p[2], p[3], p[4],
        p[5], p[6], p[7], p[8],
        p[9], p[10], p[11], p[12],
        ws_h);

    dense_nat_kernel<<<dim3(T_STEPS), dim3(128), 0, stream>>>(
        p[13], p[14], ws_h, (float*)d_out);
}

// Round 8
// 160.673 us; speedup vs baseline: 1.2067x; 1.2067x over previous
//
#include <hip/hip_runtime.h>
#include <hip/hip_bf16.h>
#include <math.h>

// Problem constants
#define T_STEPS 100
#define H_DIM   50
#define Z_DIM   10
#define OUT_DIM 65   // Z + Z*(Z+1)/2 = 10 + 55
#define KP      25   // f16 pairs per gate column

typedef _Float16 half2v __attribute__((ext_vector_type(2)));

// ---- cross-lane primitives ----
__device__ __forceinline__ float bcast_lane(float v, int lane) {
    return __uint_as_float(__builtin_amdgcn_readlane(__float_as_uint(v), lane));
}
__device__ __forceinline__ unsigned readlane_u(unsigned v, int lane) {
    return (unsigned)__builtin_amdgcn_readlane((int)v, lane);
}
// DPP cross-lane fetch (VALU speed). bound_ctrl=1 -> invalid source reads 0.
template<int CTRL>
__device__ __forceinline__ float dpp_mov(float x) {
    return __uint_as_float((unsigned)__builtin_amdgcn_update_dpp(
        0, (int)__float_as_uint(x), CTRL, 0xF, 0xF, true));
}
#define DPP_ROW_SHL1 0x101
#define DPP_SHR1     0x111
#define DPP_SHR2     0x112
#define DPP_SHR4     0x114
#define DPP_SHR8     0x118
#define DPP_BCAST15  0x142
#define DPP_BCAST31  0x143

// ---- packed f16 helpers ----
__device__ __forceinline__ unsigned pack_h2(float lo, float hi) {
#if __has_builtin(__builtin_amdgcn_cvt_pkrtz)
    return __builtin_bit_cast(unsigned, __builtin_amdgcn_cvt_pkrtz(lo, hi));
#else
    half2v p; p.x = (_Float16)lo; p.y = (_Float16)hi;
    return __builtin_bit_cast(unsigned, p);
#endif
}
__device__ __forceinline__ float fdot2h(unsigned a, unsigned b, float c) {
#if __has_builtin(__builtin_amdgcn_fdot2)
    return __builtin_amdgcn_fdot2(__builtin_bit_cast(half2v, a),
                                  __builtin_bit_cast(half2v, b), c, false);
#else
    const half2v x = __builtin_bit_cast(half2v, a);
    const half2v y = __builtin_bit_cast(half2v, b);
    return fmaf((float)x.x, (float)y.x, fmaf((float)x.y, (float)y.y, c));
#endif
}

// ---- fast math ----
__device__ __forceinline__ float fast_rcp(float x) { return __builtin_amdgcn_rcpf(x); }
__device__ __forceinline__ float fast_rsq(float x) { return __builtin_amdgcn_rsqf(x); }
__device__ __forceinline__ float fast_sigmoid(float x) {
    return fast_rcp(1.0f + __expf(-x));
}
__device__ __forceinline__ float fast_tanh(float y) {
    return 1.0f - 2.0f * fast_rcp(__expf(2.0f * y) + 1.0f);
}

__global__ __launch_bounds__(256, 1)
void gru_nat_kernel(
    const float* __restrict__ carry_init,
    const float* __restrict__ W_hr, const float* __restrict__ b_hr,
    const float* __restrict__ s_r,  const float* __restrict__ o_r,
    const float* __restrict__ W_hz, const float* __restrict__ b_hz,
    const float* __restrict__ s_z,  const float* __restrict__ o_z,
    const float* __restrict__ W_hn, const float* __restrict__ b_hn,
    const float* __restrict__ s_n,  const float* __restrict__ o_n,
    const float* __restrict__ W_dense, const float* __restrict__ b_dense,
    float* __restrict__ out)
{
    __shared__ float hs[T_STEPS][H_DIM];       // 20000 B
    __shared__ float dense[T_STEPS][OUT_DIM];  // 26000 B

    const int tid = threadIdx.x;

    // ---------------- Phase 1: recurrence, ONE wave, f16-dot2 matvec ----------------
    if (tid < 64) {
        const int  j     = tid;
        const bool valid = (j < H_DIM);
        const int  jc    = valid ? j : 0;

        // Lane j: column j of each gate's W, packed f16 pairs over K.
        // Invalid lanes get zero weights/bias -> activations exactly 0 ->
        // LN stats need no masking.
        unsigned wr[KP], wz[KP], wn[KP];
        #pragma unroll
        for (int k = 0; k < KP; ++k) {
            const int i0 = 2 * k, i1 = 2 * k + 1;
            wr[k] = pack_h2(valid ? W_hr[i0 * H_DIM + j] : 0.0f,
                            valid ? W_hr[i1 * H_DIM + j] : 0.0f);
            wz[k] = pack_h2(valid ? W_hz[i0 * H_DIM + j] : 0.0f,
                            valid ? W_hz[i1 * H_DIM + j] : 0.0f);
            wn[k] = pack_h2(valid ? W_hn[i0 * H_DIM + j] : 0.0f,
                            valid ? W_hn[i1 * H_DIM + j] : 0.0f);
        }
        // Pin: forbid rematerializing the loads inside the t-loop.
        #pragma unroll
        for (int k = 0; k < KP; ++k)
            asm volatile("" : "+v"(wr[k]), "+v"(wz[k]), "+v"(wn[k]));

        const float bjr = valid ? b_hr[jc] : 0.0f;
        const float bjz = valid ? b_hz[jc] : 0.0f;
        const float bjn = valid ? b_hn[jc] : 0.0f;
        const float sr  = s_r[jc], og_r = o_r[jc];
        const float sz  = s_z[jc], og_z = o_z[jc];
        const float sn  = s_n[jc], og_n = o_n[jc];

        float h = valid ? carry_init[jc] : 0.0f;
        const float invH = 1.0f / (float)H_DIM;

        // Packed broadcast source: even lane 2k holds (h_2k, h_{2k+1}).
        // Pairs stay inside a 16-lane row (2k even), so row_shl:1 is exact.
        float    hsl = dpp_mov<DPP_ROW_SHL1>(h);
        unsigned hpk = pack_h2(h, hsl);

        #pragma unroll 1
        for (int t = 0; t < T_STEPS; ++t) {
            // ---- three matvecs via dot2: a_j = b_j + sum_i h_i*W[i][j] ----
            float ar0 = bjr, ar1 = 0.0f;
            float az0 = bjz, az1 = 0.0f;
            float an0 = bjn, an1 = 0.0f;
            #pragma unroll
            for (int k = 0; k < KP; k += 2) {
                const unsigned s0 = readlane_u(hpk, 2 * k);
                ar0 = fdot2h(s0, wr[k], ar0);
                az0 = fdot2h(s0, wz[k], az0);
                an0 = fdot2h(s0, wn[k], an0);
                if (k + 1 < KP) {
                    const unsigned s1 = readlane_u(hpk, 2 * (k + 1));
                    ar1 = fdot2h(s1, wr[k + 1], ar1);
                    az1 = fdot2h(s1, wz[k + 1], az1);
                    an1 = fdot2h(s1, wn[k + 1], an1);
                }
            }
            const float ar = ar0 + ar1;
            const float az = az0 + az1;
            const float an = an0 + an1;

            // ---- LN stats: 6 quantities, interleaved DPP tree ----
            float mr = ar, qr = ar * ar;
            float mz = az, qz = az * az;
            float mn = an, qn = an * an;
            #define STAGE(C)                                      \
                mr += dpp_mov<C>(mr); qr += dpp_mov<C>(qr);       \
                mz += dpp_mov<C>(mz); qz += dpp_mov<C>(qz);       \
                mn += dpp_mov<C>(mn); qn += dpp_mov<C>(qn);
            STAGE(DPP_SHR1) STAGE(DPP_SHR2) STAGE(DPP_SHR4)
            STAGE(DPP_SHR8) STAGE(DPP_BCAST15) STAGE(DPP_BCAST31)
            #undef STAGE
            mr = bcast_lane(mr, 63); qr = bcast_lane(qr, 63);
            mz = bcast_lane(mz, 63); qz = bcast_lane(qz, 63);
            mn = bcast_lane(mn, 63); qn = bcast_lane(qn, 63);

            // ---- layernorm + activations ----
            const float mu_r  = mr * invH;
            const float var_r = fmaxf(qr * invH - mu_r * mu_r, 0.0f);
            const float g_r   = (ar - mu_r) * fast_rsq(var_r + 1e-6f) * sr + og_r;
            const float r     = fast_sigmoid(g_r);

            const float mu_z  = mz * invH;
            const float var_z = fmaxf(qz * invH - mu_z * mu_z, 0.0f);
            const float g_z   = (az - mu_z) * fast_rsq(var_z + 1e-6f) * sz + og_z;
            const float z     = fast_sigmoid(g_z);

            const float mu_n  = mn * invH;
            const float var_n = fmaxf(qn * invH - mu_n * mu_n, 0.0f);
            const float g_n   = (an - mu_n) * fast_rsq(var_n + 1e-6f) * sn + og_n;
            const float n     = fast_tanh(r * g_n);

            h = n + z * (h - n);                 // (1-z)*n + z*h
            if (valid) hs[t][j] = h;

            // repack broadcast source for next step
            hsl = dpp_mov<DPP_ROW_SHL1>(h);
            hpk = pack_h2(h, hsl);
        }
    }
    __syncthreads();

    // ---------------- Phase 2: dense projection (all 256 threads) ----------------
    for (int idx = tid; idx < T_STEPS * OUT_DIM; idx += 256) {
        const int t = idx / OUT_DIM;
        const int o = idx - t * OUT_DIM;
        float acc = b_dense[o];
        #pragma unroll 10
        for (int i = 0; i < H_DIM; ++i)
            acc = fmaf(hs[t][i], W_dense[i * OUT_DIM + o], acc);
        dense[t][o] = acc;
    }
    __syncthreads();

    // ---------------- Phase 3: nat transform, one thread per timestep ----------------
    if (tid < T_STEPS) {
        const int t = tid;

        float mu[Z_DIM];
        #pragma unroll
        for (int i = 0; i < Z_DIM; ++i) mu[i] = dense[t][i];

        // L packed lower-triangular, flat index tri(i)+k, tri(i)=i*(i+1)/2
        float L[55];
        #pragma unroll
        for (int f = 0; f < 55; ++f) L[f] = dense[t][Z_DIM + f];

        // softplus on the diagonal
        #pragma unroll
        for (int i = 0; i < Z_DIM; ++i) {
            const int   d = i * (i + 1) / 2 + i;
            const float x = L[d];
            L[d] = (x > 20.0f) ? x : log1pf(__expf(x));
        }

        float* outSigma = out;           // [100][10][10]
        float* outMu    = out + 10000;   // [100][10]
        float* outJ     = out + 11000;   // [100][10][10]
        float* outHnat  = out + 21000;   // [100][10]

        // Sigma = L @ L^T (symmetric) — uses L only, before in-place inversion
        #pragma unroll
        for (int a = 0; a < Z_DIM; ++a) {
            #pragma unroll
            for (int b = 0; b <= a; ++b) {
                float s = 0.0f;
                #pragma unroll
                for (int k = 0; k <= b; ++k)
                    s = fmaf(L[a * (a + 1) / 2 + k], L[b * (b + 1) / 2 + k], s);
                outSigma[t * 100 + a * 10 + b] = s;
                outSigma[t * 100 + b * 10 + a] = s;
            }
        }

        #pragma unroll
        for (int i = 0; i < Z_DIM; ++i) outMu[t * 10 + i] = mu[i];

        // In-place lower-triangular inversion
        #pragma unroll
        for (int i = 0; i < Z_DIM; ++i) {
            const float d = 1.0f / L[i * (i + 1) / 2 + i];
            float tmp[Z_DIM];
            #pragma unroll
            for (int k = 0; k < Z_DIM - 1; ++k) tmp[k] = 0.0f;
            #pragma unroll
            for (int k = 0; k < i; ++k) {
                float s = 0.0f;
                #pragma unroll
                for (int m = k; m < i; ++m)
                    s = fmaf(L[i * (i + 1) / 2 + m], L[m * (m + 1) / 2 + k], s);
                tmp[k] = -s * d;
            }
            #pragma unroll
            for (int k = 0; k < i; ++k) L[i * (i + 1) / 2 + k] = tmp[k];
            L[i * (i + 1) / 2 + i] = d;
        }
        // L now holds Linv

        // J = Linv^T @ Linv (symmetric), h_nat = J @ mu
        float hn[Z_DIM];
        #pragma unroll
        for (int a = 0; a < Z_DIM; ++a) hn[a] = 0.0f;

        #pragma unroll
        for (int a = 0; a < Z_DIM; ++a) {
            #pragma unroll
            for (int b = 0; b <= a; ++b) {
                float s = 0.0f;
                #pragma unroll
                for (int m = a; m < Z_DIM; ++m)
                    s = fmaf(L[m * (m + 1) / 2 + a], L[m * (m + 1) / 2 + b], s);
                outJ[t * 100 + a * 10 + b] = s;
                outJ[t * 100 + b * 10 + a] = s;
                hn[a] = fmaf(s, mu[b], hn[a]);
                if (b < a) hn[b] = fmaf(s, mu[a], hn[b]);
            }
        }
        #pragma unroll
        for (int a = 0; a < Z_DIM; ++a) outHnat[t * 10 + a] = hn[a];
    }
}

extern "C" void kernel_launch(void* const* d_in, const int* in_sizes, int n_in,
                              void* d_out, int out_size, void* d_ws, size_t ws_size,
                              hipStream_t stream) {
    const float* p[15];
    for (int i = 0; i < 15; ++i) p[i] = (const float*)d_in[i];
    gru_nat_kernel<<<dim3(1), dim3(256), 0, stream>>>(
        p[0],
        p[1], p[2], p[3], p[4],
        p[5], p[6], p[7], p[8],
        p[9], p[10], p[11], p[12],
        p[13], p[14],
        (float*)d_out);
}

// Round 9
// 137.512 us; speedup vs baseline: 1.4099x; 1.1684x over previous
//
#include <hip/hip_runtime.h>
#include <hip/hip_bf16.h>
#include <math.h>

// Problem constants
#define T_STEPS 100
#define H_DIM   50
#define Z_DIM   10
#define OUT_DIM 65   // Z + Z*(Z+1)/2 = 10 + 55
#define KP      25   // f16 pairs per gate column

typedef _Float16 half2v __attribute__((ext_vector_type(2)));

// ---- cross-lane primitives ----
__device__ __forceinline__ float bcast_lane(float v, int lane) {
    return __uint_as_float(__builtin_amdgcn_readlane(__float_as_uint(v), lane));
}
__device__ __forceinline__ unsigned readlane_u(unsigned v, int lane) {
    return (unsigned)__builtin_amdgcn_readlane((int)v, lane);
}
// DPP cross-lane fetch (VALU speed). bound_ctrl=1 -> invalid source reads 0.
template<int CTRL>
__device__ __forceinline__ float dpp_mov(float x) {
    return __uint_as_float((unsigned)__builtin_amdgcn_update_dpp(
        0, (int)__float_as_uint(x), CTRL, 0xF, 0xF, true));
}
#define DPP_ROW_SHL1 0x101   // lane i <- lane i+1
#define DPP_SHR1     0x111
#define DPP_SHR2     0x112
#define DPP_SHR4     0x114
#define DPP_SHR8     0x118
#define DPP_BCAST15  0x142
#define DPP_BCAST31  0x143

// ---- packed f16 helpers ----
__device__ __forceinline__ unsigned pack_h2(float lo, float hi) {
#if __has_builtin(__builtin_amdgcn_cvt_pkrtz)
    return __builtin_bit_cast(unsigned, __builtin_amdgcn_cvt_pkrtz(lo, hi));
#else
    half2v p; p.x = (_Float16)lo; p.y = (_Float16)hi;
    return __builtin_bit_cast(unsigned, p);
#endif
}
__device__ __forceinline__ float fdot2h(unsigned a, unsigned b, float c) {
#if __has_builtin(__builtin_amdgcn_fdot2)
    return __builtin_amdgcn_fdot2(__builtin_bit_cast(half2v, a),
                                  __builtin_bit_cast(half2v, b), c, false);
#else
    const half2v x = __builtin_bit_cast(half2v, a);
    const half2v y = __builtin_bit_cast(half2v, b);
    return fmaf((float)x.x, (float)y.x, fmaf((float)x.y, (float)y.y, c));
#endif
}

// ---- fast math ----
__device__ __forceinline__ float fast_rcp(float x) { return __builtin_amdgcn_rcpf(x); }
__device__ __forceinline__ float fast_rsq(float x) { return __builtin_amdgcn_rsqf(x); }
__device__ __forceinline__ float fast_sigmoid(float x) {
    return fast_rcp(1.0f + __expf(-x));
}
__device__ __forceinline__ float fast_tanh(float y) {
    return 1.0f - 2.0f * fast_rcp(__expf(2.0f * y) + 1.0f);
}

// =====================================================================
// Kernel 1: serial recurrence. ONE wave, f16-dot2 matvec, weights as
// 75 packed dwords per lane (minimal footprint -> minimal parking).
// h history -> ws as [T][64] f32.
// =====================================================================
__global__ __launch_bounds__(64, 1)
void gru_recur_kernel(
    const float* __restrict__ carry_init,
    const float* __restrict__ W_hr, const float* __restrict__ b_hr,
    const float* __restrict__ s_r,  const float* __restrict__ o_r,
    const float* __restrict__ W_hz, const float* __restrict__ b_hz,
    const float* __restrict__ s_z,  const float* __restrict__ o_z,
    const float* __restrict__ W_hn, const float* __restrict__ b_hn,
    const float* __restrict__ s_n,  const float* __restrict__ o_n,
    float* __restrict__ ws_h)
{
    const int  j     = threadIdx.x;
    const bool valid = (j < H_DIM);
    const int  jc    = valid ? j : 0;

    // Lane j: column j of each gate's W, packed f16 pairs over K.
    // Invalid lanes get zero weights/bias -> activations exactly 0 ->
    // LN stats need no masking.
    unsigned wr[KP], wz[KP], wn[KP];
    #pragma unroll
    for (int k = 0; k < KP; ++k) {
        const int i0 = 2 * k, i1 = 2 * k + 1;
        wr[k] = pack_h2(valid ? W_hr[i0 * H_DIM + j] : 0.0f,
                        valid ? W_hr[i1 * H_DIM + j] : 0.0f);
        wz[k] = pack_h2(valid ? W_hz[i0 * H_DIM + j] : 0.0f,
                        valid ? W_hz[i1 * H_DIM + j] : 0.0f);
        wn[k] = pack_h2(valid ? W_hn[i0 * H_DIM + j] : 0.0f,
                        valid ? W_hn[i1 * H_DIM + j] : 0.0f);
    }
    // Pin: forbid rematerializing the loads/converts inside the t-loop.
    #pragma unroll
    for (int k = 0; k < KP; ++k)
        asm volatile("" : "+v"(wr[k]), "+v"(wz[k]), "+v"(wn[k]));

    const float bjr = valid ? b_hr[jc] : 0.0f;
    const float bjz = valid ? b_hz[jc] : 0.0f;
    const float bjn = valid ? b_hn[jc] : 0.0f;
    const float sr  = s_r[jc], og_r = o_r[jc];
    const float sz  = s_z[jc], og_z = o_z[jc];
    const float sn  = s_n[jc], og_n = o_n[jc];

    float h = valid ? carry_init[jc] : 0.0f;
    const float invH = 1.0f / (float)H_DIM;

    // Packed broadcast source: even lane 2k holds (h_2k, h_{2k+1}).
    // row_shl:1 (lane i <- i+1) stays in-row since 2k is even.
    float    hsl = dpp_mov<DPP_ROW_SHL1>(h);
    unsigned hpk = pack_h2(h, hsl);

    #pragma unroll 1
    for (int t = 0; t < T_STEPS; ++t) {
        // ---- three matvecs via dot2: a_j = b_j + sum_i h_i*W[i][j] ----
        float ar0 = bjr, ar1 = 0.0f;
        float az0 = bjz, az1 = 0.0f;
        float an0 = bjn, an1 = 0.0f;
        #pragma unroll
        for (int k = 0; k < KP; k += 2) {
            const unsigned s0 = readlane_u(hpk, 2 * k);
            ar0 = fdot2h(s0, wr[k], ar0);
            az0 = fdot2h(s0, wz[k], az0);
            an0 = fdot2h(s0, wn[k], an0);
            if (k + 1 < KP) {
                const unsigned s1 = readlane_u(hpk, 2 * (k + 1));
                ar1 = fdot2h(s1, wr[k + 1], ar1);
                az1 = fdot2h(s1, wz[k + 1], az1);
                an1 = fdot2h(s1, wn[k + 1], an1);
            }
        }
        const float ar = ar0 + ar1;
        const float az = az0 + az1;
        const float an = an0 + an1;

        // ---- LN stats: 6 quantities, interleaved DPP tree ----
        float mr = ar, qr = ar * ar;
        float mz = az, qz = az * az;
        float mn = an, qn = an * an;
        #define STAGE(C)                                      \
            mr += dpp_mov<C>(mr); qr += dpp_mov<C>(qr);       \
            mz += dpp_mov<C>(mz); qz += dpp_mov<C>(qz);       \
            mn += dpp_mov<C>(mn); qn += dpp_mov<C>(qn);
        STAGE(DPP_SHR1) STAGE(DPP_SHR2) STAGE(DPP_SHR4)
        STAGE(DPP_SHR8) STAGE(DPP_BCAST15) STAGE(DPP_BCAST31)
        #undef STAGE
        mr = bcast_lane(mr, 63); qr = bcast_lane(qr, 63);
        mz = bcast_lane(mz, 63); qz = bcast_lane(qz, 63);
        mn = bcast_lane(mn, 63); qn = bcast_lane(qn, 63);

        // ---- layernorm + activations ----
        const float mu_r  = mr * invH;
        const float var_r = fmaxf(qr * invH - mu_r * mu_r, 0.0f);
        const float g_r   = (ar - mu_r) * fast_rsq(var_r + 1e-6f) * sr + og_r;
        const float r     = fast_sigmoid(g_r);

        const float mu_z  = mz * invH;
        const float var_z = fmaxf(qz * invH - mu_z * mu_z, 0.0f);
        const float g_z   = (az - mu_z) * fast_rsq(var_z + 1e-6f) * sz + og_z;
        const float z     = fast_sigmoid(g_z);

        const float mu_n  = mn * invH;
        const float var_n = fmaxf(qn * invH - mu_n * mu_n, 0.0f);
        const float g_n   = (an - mu_n) * fast_rsq(var_n + 1e-6f) * sn + og_n;
        const float n     = fast_tanh(r * g_n);

        h = n + z * (h - n);                 // (1-z)*n + z*h
        ws_h[t * 64 + j] = h;                // unconditional 64-wide store

        // repack broadcast source for next step
        hsl = dpp_mov<DPP_ROW_SHL1>(h);
        hpk = pack_h2(h, hsl);
    }
}

// =====================================================================
// Kernel 2: dense projection + nat transform. One block per timestep,
// parallel across CUs.
// =====================================================================
__global__ __launch_bounds__(128)
void dense_nat_kernel(
    const float* __restrict__ W_dense, const float* __restrict__ b_dense,
    const float* __restrict__ ws_h, float* __restrict__ out)
{
    const int t   = blockIdx.x;
    const int tid = threadIdx.x;

    __shared__ float hloc[H_DIM];
    __shared__ float dl  [OUT_DIM];
    __shared__ float Lp  [55];
    __shared__ float Li  [55];
    __shared__ float Jsh [100];

    if (tid < H_DIM) hloc[tid] = ws_h[t * 64 + tid];
    __syncthreads();

    if (tid < OUT_DIM) {
        float acc = b_dense[tid];
        #pragma unroll
        for (int i = 0; i < H_DIM; ++i)
            acc = fmaf(hloc[i], W_dense[i * OUT_DIM + tid], acc);
        dl[tid] = acc;
    }
    __syncthreads();

    // Lp = packed lower-tri L with softplus applied to diagonal entries.
    if (tid < 55) {
        float v = dl[Z_DIM + tid];
        const bool isd = (tid==0)|(tid==2)|(tid==5)|(tid==9)|(tid==14)|
                         (tid==20)|(tid==27)|(tid==35)|(tid==44)|(tid==54);
        if (isd) v = (v > 20.0f) ? v : log1pf(__expf(v));
        Lp[tid] = v;
    }
    __syncthreads();

    float* outSigma = out;           // [100][10][10]
    float* outMu    = out + 10000;   // [100][10]
    float* outJ     = out + 11000;   // [100][10][10]
    float* outHnat  = out + 21000;   // [100][10]

    // Map flat tri index -> (a,b), a >= b
    int a = 0;
    {
        #pragma unroll
        for (int x = 1; x < Z_DIM; ++x)
            if (tid >= x * (x + 1) / 2) a = x;
    }
    const int b = tid - a * (a + 1) / 2;

    // Sigma = L @ L^T (one entry per thread)
    if (tid < 55) {
        float s = 0.0f;
        for (int k = 0; k <= b; ++k)
            s = fmaf(Lp[a * (a + 1) / 2 + k], Lp[b * (b + 1) / 2 + k], s);
        outSigma[t * 100 + a * 10 + b] = s;
        outSigma[t * 100 + b * 10 + a] = s;
    }
    if (tid >= 64 && tid < 64 + Z_DIM) outMu[t * 10 + (tid - 64)] = dl[tid - 64];
    __syncthreads();

    // Linv by forward substitution (serial, tiny)
    if (tid == 0) {
        #pragma unroll
        for (int i = 0; i < Z_DIM; ++i) {
            const float d = 1.0f / Lp[i * (i + 1) / 2 + i];
            #pragma unroll
            for (int k = 0; k < i; ++k) {
                float s = 0.0f;
                for (int m = k; m < i; ++m)
                    s = fmaf(Lp[i * (i + 1) / 2 + m], Li[m * (m + 1) / 2 + k], s);
                Li[i * (i + 1) / 2 + k] = -s * d;
            }
            Li[i * (i + 1) / 2 + i] = d;
        }
    }
    __syncthreads();

    // J = Linv^T @ Linv (one entry per thread)
    if (tid < 55) {
        float s = 0.0f;
        for (int m = a; m < Z_DIM; ++m)
            s = fmaf(Li[m * (m + 1) / 2 + a], Li[m * (m + 1) / 2 + b], s);
        outJ[t * 100 + a * 10 + b] = s;
        outJ[t * 100 + b * 10 + a] = s;
        Jsh[a * 10 + b] = s;
        Jsh[b * 10 + a] = s;
    }
    __syncthreads();

    // h_nat = J @ mu
    if (tid < Z_DIM) {
        float s = 0.0f;
        #pragma unroll
        for (int k = 0; k < Z_DIM; ++k)
            s = fmaf(Jsh[tid * 10 + k], dl[k], s);
        outHnat[t * 10 + tid] = s;
    }
}

extern "C" void kernel_launch(void* const* d_in, const int* in_sizes, int n_in,
                              void* d_out, int out_size, void* d_ws, size_t ws_size,
                              hipStream_t stream) {
    const float* p[15];
    for (int i = 0; i < 15; ++i) p[i] = (const float*)d_in[i];
    float* ws_h = (float*)d_ws;   // [T_STEPS][64] f32 = 25600 B

    gru_recur_kernel<<<dim3(1), dim3(64), 0, stream>>>(
        p[0],
        p[1], p[2], p[3], p[4],
        p[5], p[6], p[7], p[8],
        p[9], p[10], p[11], p[12],
        ws_h);

    dense_nat_kernel<<<dim3(T_STEPS), dim3(128), 0, stream>>>(
        p[13], p[14], ws_h, (float*)d_out);
}